// Round 2
// baseline (1665.579 us; speedup 1.0000x reference)
//
#include <hip/hip_runtime.h>
#include <hip/hip_cooperative_groups.h>

namespace cg = cooperative_groups;

// Decoder: B=64, T=32, R=49, E=512, L=2, V=30000. fp32 in/out, bf16 MFMA inside.
#define B_ 64
#define T_ 32
#define R_ 49
#define E_ 512
#define V_ 30000

using bfrag = __attribute__((ext_vector_type(8))) short;   // 8 bf16 (4 VGPRs)
using ffrag = __attribute__((ext_vector_type(4))) float;   // 4 fp32 acc

__device__ __forceinline__ float bf2f(short u) {
    union { unsigned u32; float f; } x;
    x.u32 = ((unsigned)(unsigned short)u) << 16;
    return x.f;
}
__device__ __forceinline__ unsigned short f2bf(float f) {
    union { float f; unsigned u; } x; x.f = f;
    unsigned r = x.u + 0x7fffu + ((x.u >> 16) & 1u);   // RNE
    return (unsigned short)(r >> 16);
}
__device__ __forceinline__ float sigm(float x) { return 1.f / (1.f + __expf(-x)); }

#define GLDS(g, l) __builtin_amdgcn_global_load_lds( \
    (const __attribute__((address_space(1))) void*)(g), \
    (__attribute__((address_space(3))) void*)(l), 16, 0, 0)

// ---------------------------------------------------------------------------
// fp32 -> bf16 bulk convert. n8 = elem_count/8.
// ---------------------------------------------------------------------------
__global__ __launch_bounds__(256)
void cvt_kernel(const float* __restrict__ src, unsigned short* __restrict__ dst, int n8)
{
    int i = blockIdx.x * 256 + threadIdx.x;
    if (i >= n8) return;
    const float4* s = (const float4*)src + (size_t)i * 2;
    float4 a = s[0], b = s[1];
    bfrag o;
    o[0] = (short)f2bf(a.x); o[1] = (short)f2bf(a.y);
    o[2] = (short)f2bf(a.z); o[3] = (short)f2bf(a.w);
    o[4] = (short)f2bf(b.x); o[5] = (short)f2bf(b.y);
    o[6] = (short)f2bf(b.z); o[7] = (short)f2bf(b.w);
    *(bfrag*)(dst + (size_t)i * 8) = o;
}

// ---------------------------------------------------------------------------
// C = A @ W^T (+bias1+bias2), fp32 out. A:[M,K] bf16, W:[N,K] bf16, bias fp32.
// m97 structure: 128x128 tile, BK=32, global_load_lds w=16, mfma 16x16x32 bf16.
// (XCD swizzle removed: R1 showed FETCH drop but dur +5% — not fetch-bound.)
// ---------------------------------------------------------------------------
__global__ __launch_bounds__(256)
void gemm_bt(const unsigned short* __restrict__ A,
             const unsigned short* __restrict__ W,
             const float* __restrict__ bias1,
             const float* __restrict__ bias2,
             float* __restrict__ outp,
             int M, int N, int K)
{
    __shared__ __align__(16) unsigned short As[128 * 32];
    __shared__ __align__(16) unsigned short Bs[128 * 32];
    const int tid  = threadIdx.x;
    const int wave = tid >> 6, lane = tid & 63;
    const int lrow = lane & 15, kq = lane >> 4;
    const int m0 = blockIdx.x * 128, n0 = blockIdx.y * 128;
    const int wm = (wave >> 1) * 64, wn = (wave & 1) * 64;

    ffrag acc[4][4];
#pragma unroll
    for (int i = 0; i < 4; i++)
#pragma unroll
        for (int j = 0; j < 4; j++) acc[i][j] = ffrag{0.f, 0.f, 0.f, 0.f};

    const int ca = tid, cb = 256 + tid;
    const int ar0 = m0 + (ca >> 2), ar1 = m0 + (cb >> 2);
    const int k8a = (ca & 3) * 8, k8b = (cb & 3) * 8;
    const int wr0 = min(n0 + (ca >> 2), N - 1);   // clamp W rows (N tail)
    const int wr1 = min(n0 + (cb >> 2), N - 1);

    unsigned short* ldsA0 = As + (wave * 64) * 8;          // wave-uniform bases
    unsigned short* ldsA1 = As + (256 + wave * 64) * 8;
    unsigned short* ldsB0 = Bs + (wave * 64) * 8;
    unsigned short* ldsB1 = Bs + (256 + wave * 64) * 8;

    for (int k0 = 0; k0 < K; k0 += 32) {
        GLDS(A + (size_t)ar0 * K + k0 + k8a, ldsA0);
        GLDS(A + (size_t)ar1 * K + k0 + k8b, ldsA1);
        GLDS(W + (size_t)wr0 * K + k0 + k8a, ldsB0);
        GLDS(W + (size_t)wr1 * K + k0 + k8b, ldsB1);
        __syncthreads();
        bfrag af[4], bw[4];
#pragma unroll
        for (int i = 0; i < 4; i++)
            af[i] = *(const bfrag*)(As + (wm + i * 16 + lrow) * 32 + kq * 8);
#pragma unroll
        for (int j = 0; j < 4; j++)
            bw[j] = *(const bfrag*)(Bs + (wn + j * 16 + lrow) * 32 + kq * 8);
#pragma unroll
        for (int i = 0; i < 4; i++)
#pragma unroll
            for (int j = 0; j < 4; j++)
                acc[i][j] = __builtin_amdgcn_mfma_f32_16x16x32_bf16(af[i], bw[j], acc[i][j], 0, 0, 0);
        __syncthreads();
    }

    // epilogue: C/D layout col=lane&15, row=(lane>>4)*4+reg  [m89-verified]
#pragma unroll
    for (int j = 0; j < 4; j++) {
        int col  = n0 + wn + j * 16 + lrow;
        int colc = min(col, N - 1);
        float bs = 0.f;
        if (bias1) bs += bias1[colc];
        if (bias2) bs += bias2[colc];
        bool ok = (col < N);
#pragma unroll
        for (int i = 0; i < 4; i++) {
            int rbase = m0 + wm + i * 16 + kq * 4;
#pragma unroll
            for (int r = 0; r < 4; r++) {
                float v = acc[i][j][r] + bs;
                if (ok) outp[(size_t)(rbase + r) * N + col] = v;
            }
        }
    }
}

// ---------------------------------------------------------------------------
// Persistent skewed 2-layer LSTM. One cooperative launch, 256 blocks (1/CU).
// Iteration k: blocks 0..127 = layer1@t=k, blocks 128..255 = layer2@t=k-1
// (independent). grid.sync() between iterations carries the dependence:
// iter k writes H0[k+1]/Htop[k]; iter k+1 reads H0[k+1] (layer2) — 1 sync apart.
// Weights (Wih+Whh slice, 128 KB/block) staged ONCE into LDS in MFMA
// fragment order -> lane-contiguous conflict-free ds_read_b128 every step.
// Cell state c lives in a register for the entire recurrence (final c unused).
// ---------------------------------------------------------------------------
__global__ __launch_bounds__(256, 1)
void lstm_persist(const unsigned short* __restrict__ Wbih,   // [L,2048,512] bf16
                  const unsigned short* __restrict__ Wbhh,   // [L,2048,512] bf16
                  const unsigned short* __restrict__ Aemb,   // [T*B,E] bf16
                  const float* __restrict__ b_ih,            // [L,4E] fp32
                  const float* __restrict__ b_hh,            // [L,4E] fp32
                  unsigned short* __restrict__ H0,           // [(T+1),B,E] bf16
                  unsigned short* __restrict__ Htop,         // [(T+1),B,E] bf16
                  const float* __restrict__ c0,
                  const float* __restrict__ c1)
{
    cg::grid_group grid = cg::this_grid();

    // sW: [mat(2)][gate(4)][kiter(16)][lane(64)][8 bf16] = 128 KB
    __shared__ __align__(16) unsigned short sW[2 * 4 * 16 * 512];
    __shared__ float gb[4][16][17];   // [gate][b][e], +1 pad

    const int layer = blockIdx.x >> 7;
    const int blk   = blockIdx.x & 127;
    const int tid  = threadIdx.x;
    const int wave = tid >> 6, lane = tid & 63;
    const int lrow = lane & 15, kq = lane >> 4;
    const int b0 = (blk & 3) * 16;
    const int e0 = (blk >> 2) * 16;
    const int wr = wave * 512 + e0 + lrow;   // W row (gate = wave)
    const size_t BE = (size_t)B_ * E_;

    const unsigned short* Wih = Wbih + (size_t)layer * 2048 * 512;
    const unsigned short* Whh = Wbhh + (size_t)layer * 2048 * 512;

    // --- stage weights into LDS (fragment order; GLDS: per-lane global src,
    //     wave-uniform LDS dst + lane*16B == exactly our layout) ---
#pragma unroll
    for (int it = 0; it < 16; ++it)
        GLDS(Wih + (size_t)wr * 512 + it * 32 + kq * 8, sW + (size_t)(wave * 16 + it) * 512);
#pragma unroll
    for (int it = 0; it < 16; ++it)
        GLDS(Whh + (size_t)wr * 512 + it * 32 + kq * 8, sW + (size_t)((4 + wave) * 16 + it) * 512);

    // per-thread elementwise coordinates + bias preload + register cell state
    const int m = tid >> 4, el = tid & 15;
    const int b = b0 + m, e = e0 + el;
    const float* bih = b_ih + layer * 2048;
    const float* bhh = b_hh + layer * 2048;
    const float bi = bih[e]        + bhh[e];
    const float bf = bih[512 + e]  + bhh[512 + e];
    const float bg = bih[1024 + e] + bhh[1024 + e];
    const float bo = bih[1536 + e] + bhh[1536 + e];
    float creg = (layer ? c1 : c0)[(size_t)b * 512 + e];

    const unsigned short* sWi = sW + (size_t)wave * 16 * 512;        // this gate, Wih
    const unsigned short* sWh = sW + (size_t)(4 + wave) * 16 * 512;  // this gate, Whh

    __syncthreads();   // drains GLDS (vmcnt) + block barrier

    for (int k = 0; k <= T_; ++k) {
        const int t = layer ? (k - 1) : k;
        if (t >= 0 && t < T_) {
            const unsigned short* xin   = layer ? (H0 + (size_t)(t + 1) * BE)
                                                : (Aemb + (size_t)t * BE);
            const unsigned short* hprev = layer ? (Htop + (size_t)t * BE)
                                                : (H0 + (size_t)t * BE);
            unsigned short* hout        = layer ? (Htop + (size_t)(t + 1) * BE)
                                                : (H0 + (size_t)(t + 1) * BE);

            ffrag acc = {0.f, 0.f, 0.f, 0.f};
#pragma unroll
            for (int i = 0; i < 16; ++i) {
                bfrag a = *(const bfrag*)(xin + (b0 + lrow) * 512 + i * 32 + kq * 8);
                bfrag w = *(const bfrag*)(sWi + (i * 64 + lane) * 8);
                acc = __builtin_amdgcn_mfma_f32_16x16x32_bf16(a, w, acc, 0, 0, 0);
            }
#pragma unroll
            for (int i = 0; i < 16; ++i) {
                bfrag a = *(const bfrag*)(hprev + (b0 + lrow) * 512 + i * 32 + kq * 8);
                bfrag w = *(const bfrag*)(sWh + (i * 64 + lane) * 8);
                acc = __builtin_amdgcn_mfma_f32_16x16x32_bf16(a, w, acc, 0, 0, 0);
            }

#pragma unroll
            for (int r = 0; r < 4; r++) gb[wave][kq * 4 + r][lrow] = acc[r];
            __syncthreads();

            float gi = gb[0][m][el] + bi;
            float gf = gb[1][m][el] + bf;
            float gg = gb[2][m][el] + bg;
            float go = gb[3][m][el] + bo;
            float cn = sigm(gf) * creg + sigm(gi) * tanhf(gg);
            float hn = sigm(go) * tanhf(cn);
            creg = cn;
            hout[(size_t)b * 512 + e] = f2bf(hn);
        }
        grid.sync();   // device-scope fence + barrier; also orders gb reuse
    }
}

// ---------------------------------------------------------------------------
// Attention over all (b,t) at once. block = one (b,t).
// Z[b*T+t] = [h_top(bf16 copy) | context(bf16)]. features fp32.
// ---------------------------------------------------------------------------
__global__ __launch_bounds__(256)
void attn_kernel(const float* __restrict__ features,          // [B,R,E] fp32
                 const unsigned short* __restrict__ Htop,     // [(T+1),B,E] bf16
                 unsigned short* __restrict__ Z)               // [B*T, 2E] bf16
{
    const int bt = blockIdx.x;            // = b*T + t
    const int b = bt >> 5, t = bt & 31;
    const unsigned short* h = Htop + ((size_t)(t + 1) * B_ + b) * E_;
    const float* f = features + (size_t)b * R_ * E_;
    const int tid = threadIdx.x, wave = tid >> 6, lane = tid & 63;

    __shared__ float hf[E_];
    __shared__ float sc[64];
    hf[tid]       = bf2f((short)h[tid]);
    hf[256 + tid] = bf2f((short)h[256 + tid]);
    __syncthreads();

    for (int r = wave; r < R_; r += 4) {
        const float4* fr = (const float4*)(f + r * E_ + lane * 8);
        float4 v0 = fr[0], v1 = fr[1];
        const float* hp = hf + lane * 8;
        float s = v0.x * hp[0] + v0.y * hp[1] + v0.z * hp[2] + v0.w * hp[3]
                + v1.x * hp[4] + v1.y * hp[5] + v1.z * hp[6] + v1.w * hp[7];
        for (int off = 32; off; off >>= 1) s += __shfl_down(s, off);
        if (lane == 0) sc[r] = s;
    }
    __syncthreads();
    if (tid < 64) {
        float v = (tid < R_) ? sc[tid] : -3.4e38f;
        float mx = v;
        for (int off = 32; off; off >>= 1) mx = fmaxf(mx, __shfl_xor(mx, off));
        float ex = (tid < R_) ? __expf(v - mx) : 0.f;
        float sum = ex;
        for (int off = 32; off; off >>= 1) sum += __shfl_xor(sum, off);
        if (tid < R_) sc[tid] = ex / sum;
    }
    __syncthreads();

    const int e0 = tid * 2;
    float c0 = 0.f, c1 = 0.f;
    for (int r = 0; r < R_; r++) {
        float a = sc[r];
        c0 += a * f[r * E_ + e0];
        c1 += a * f[r * E_ + e0 + 1];
    }
    unsigned short* zr = Z + (size_t)bt * (2 * E_);
    zr[e0] = h[e0]; zr[e0 + 1] = h[e0 + 1];          // bf16 copy of h_top
    zr[E_ + e0]     = f2bf(c0);
    zr[E_ + e0 + 1] = f2bf(c1);
}

// ---------------------------------------------------------------------------
// Init: mean_f -> c0/c1 (fp32) + h0 (bf16, both layers); gather+convert
// embeddings into Aemb [T*B, E] bf16.
// ---------------------------------------------------------------------------
__global__ __launch_bounds__(256)
void init_kernel(const float* __restrict__ features,
                 const int* __restrict__ captions,
                 const float* __restrict__ embed,
                 float* __restrict__ c0, float* __restrict__ c1,
                 unsigned short* __restrict__ H0, unsigned short* __restrict__ Htop,
                 unsigned short* __restrict__ Aemb)
{
    const int blk = blockIdx.x, tid = threadIdx.x;
    if (blk < 128) {
        int g = blk * 256 + tid;          // 0..B*E-1
        int b = g >> 9, e = g & 511;
        float s = 0.f;
        for (int r = 0; r < R_; r++) s += features[((size_t)b * R_ + r) * E_ + e];
        float mean = s * (1.f / 49.f);
        c0[g] = mean; c1[g] = mean;
        unsigned short mb = f2bf(mean);
        H0[g] = mb; Htop[g] = mb;
    } else {
        int idx = (blk - 128) * 256 + tid;        // chunk of 8 elems
        int row = idx >> 6, k8 = (idx & 63) * 8;  // row = t*B+b
        int bb = row & 63, tt = row >> 6;
        int tok = captions[bb * T_ + tt];
        const float4* s = (const float4*)(embed + (size_t)tok * E_ + k8);
        float4 a = s[0], bq = s[1];
        bfrag o;
        o[0] = (short)f2bf(a.x);  o[1] = (short)f2bf(a.y);
        o[2] = (short)f2bf(a.z);  o[3] = (short)f2bf(a.w);
        o[4] = (short)f2bf(bq.x); o[5] = (short)f2bf(bq.y);
        o[6] = (short)f2bf(bq.z); o[7] = (short)f2bf(bq.w);
        *(bfrag*)(Aemb + (size_t)row * E_ + k8) = o;
    }
}

// ---------------------------------------------------------------------------
extern "C" void kernel_launch(void* const* d_in, const int* in_sizes, int n_in,
                              void* d_out, int out_size, void* d_ws, size_t ws_size,
                              hipStream_t stream)
{
    const float* features = (const float*)d_in[0];
    const int*   captions = (const int*)d_in[1];
    const float* embed    = (const float*)d_in[2];
    const float* W_ih     = (const float*)d_in[3];
    const float* W_hh     = (const float*)d_in[4];
    const float* b_ih     = (const float*)d_in[5];
    const float* b_hh     = (const float*)d_in[6];
    const float* W_lin    = (const float*)d_in[7];
    const float* b_lin    = (const float*)d_in[8];
    float* out = (float*)d_out;

    char* ws = (char*)d_ws;
    unsigned short* H0     = (unsigned short*)(ws + 16777216);   // [(T+1),B,E] bf16
    unsigned short* Htop   = (unsigned short*)(ws + 18939904);   // [(T+1),B,E] bf16
    float*          c0     = (float*)(ws + 21102592);            // [B,E] fp32
    float*          c1     = (float*)(ws + 21233664);            // [B,E] fp32
    unsigned short* Z      = (unsigned short*)(ws + 21364736);   // [B*T,2E] bf16
    unsigned short* Aemb   = (unsigned short*)(ws + 25559040);   // [T*B,E] bf16
    unsigned short* Wb_ih  = (unsigned short*)(ws + 27656192);   // [L,4E,E] bf16
    unsigned short* Wb_hh  = (unsigned short*)(ws + 31850496);   // [L,4E,E] bf16
    unsigned short* Wb_lin = (unsigned short*)(ws + 36044800);   // [V,2E] bf16 61.4 MB

    // fp32 -> bf16 weight conversions
    cvt_kernel<<<1024, 256, 0, stream>>>(W_ih, Wb_ih, 2 * 2048 * 512 / 8);
    cvt_kernel<<<1024, 256, 0, stream>>>(W_hh, Wb_hh, 2 * 2048 * 512 / 8);
    cvt_kernel<<<15000, 256, 0, stream>>>(W_lin, Wb_lin, V_ * 1024 / 8);

    init_kernel<<<640, 256, 0, stream>>>(features, captions, embed, c0, c1, H0, Htop, Aemb);

    // Whole recurrence in ONE cooperative launch (33 grid.sync steps).
    {
        const unsigned short* a0 = Wb_ih; const unsigned short* a1 = Wb_hh;
        const unsigned short* a2 = Aemb;
        const float* a3 = b_ih; const float* a4 = b_hh;
        unsigned short* a5 = H0; unsigned short* a6 = Htop;
        const float* a7 = c0; const float* a8 = c1;
        void* args[] = { &a0, &a1, &a2, &a3, &a4, &a5, &a6, &a7, &a8 };
        hipLaunchCooperativeKernel((void*)lstm_persist, dim3(256), dim3(256),
                                   args, 0, stream);
    }

    attn_kernel<<<B_ * T_, 256, 0, stream>>>(features, Htop, Z);

    // logits = Z @ W_lin^T + b_lin  -> fp32 out [B*T, V]
    gemm_bt<<<dim3(16, 235), 256, 0, stream>>>(Z, Wb_lin, b_lin, nullptr, out, 2048, V_, 1024);

    (void)in_sizes; (void)n_in; (void)out_size; (void)ws_size;
}

// Round 3
// 984.136 us; speedup vs baseline: 1.6924x; 1.6924x over previous
//
#include <hip/hip_runtime.h>

// Decoder: B=64, T=32, R=49, E=512, L=2, V=30000. fp32 in/out, bf16 MFMA inside.
#define B_ 64
#define T_ 32
#define R_ 49
#define E_ 512
#define V_ 30000

using bfrag = __attribute__((ext_vector_type(8))) short;   // 8 bf16 (4 VGPRs)
using ffrag = __attribute__((ext_vector_type(4))) float;   // 4 fp32 acc

__device__ __forceinline__ float bf2f(short u) {
    union { unsigned u32; float f; } x;
    x.u32 = ((unsigned)(unsigned short)u) << 16;
    return x.f;
}
__device__ __forceinline__ unsigned short f2bf(float f) {
    union { float f; unsigned u; } x; x.f = f;
    unsigned r = x.u + 0x7fffu + ((x.u >> 16) & 1u);   // RNE
    return (unsigned short)(r >> 16);
}
__device__ __forceinline__ float sigm(float x) { return 1.f / (1.f + __expf(-x)); }

#define GLDS(g, l) __builtin_amdgcn_global_load_lds( \
    (const __attribute__((address_space(1))) void*)(g), \
    (__attribute__((address_space(3))) void*)(l), 16, 0, 0)

// ---------------------------------------------------------------------------
// fp32 -> bf16 bulk convert. n8 = elem_count/8.
// ---------------------------------------------------------------------------
__global__ __launch_bounds__(256)
void cvt_kernel(const float* __restrict__ src, unsigned short* __restrict__ dst, int n8)
{
    int i = blockIdx.x * 256 + threadIdx.x;
    if (i >= n8) return;
    const float4* s = (const float4*)src + (size_t)i * 2;
    float4 a = s[0], b = s[1];
    bfrag o;
    o[0] = (short)f2bf(a.x); o[1] = (short)f2bf(a.y);
    o[2] = (short)f2bf(a.z); o[3] = (short)f2bf(a.w);
    o[4] = (short)f2bf(b.x); o[5] = (short)f2bf(b.y);
    o[6] = (short)f2bf(b.z); o[7] = (short)f2bf(b.w);
    *(bfrag*)(dst + (size_t)i * 8) = o;
}

// ---------------------------------------------------------------------------
// C = A @ W^T (+bias1+bias2), fp32 out. A:[M,K] bf16, W:[N,K] bf16, bias fp32.
// m97 structure: 128x128 tile, BK=32, global_load_lds w=16, mfma 16x16x32 bf16.
// No XCD swizzle: R1 A/B showed FETCH 252->149 MB but dur +5% (not fetch-bound).
// ---------------------------------------------------------------------------
__global__ __launch_bounds__(256)
void gemm_bt(const unsigned short* __restrict__ A,
             const unsigned short* __restrict__ W,
             const float* __restrict__ bias1,
             const float* __restrict__ bias2,
             float* __restrict__ outp,
             int M, int N, int K)
{
    __shared__ __align__(16) unsigned short As[128 * 32];
    __shared__ __align__(16) unsigned short Bs[128 * 32];
    const int tid  = threadIdx.x;
    const int wave = tid >> 6, lane = tid & 63;
    const int lrow = lane & 15, kq = lane >> 4;
    const int m0 = blockIdx.x * 128, n0 = blockIdx.y * 128;
    const int wm = (wave >> 1) * 64, wn = (wave & 1) * 64;

    ffrag acc[4][4];
#pragma unroll
    for (int i = 0; i < 4; i++)
#pragma unroll
        for (int j = 0; j < 4; j++) acc[i][j] = ffrag{0.f, 0.f, 0.f, 0.f};

    const int ca = tid, cb = 256 + tid;
    const int ar0 = m0 + (ca >> 2), ar1 = m0 + (cb >> 2);
    const int k8a = (ca & 3) * 8, k8b = (cb & 3) * 8;
    const int wr0 = min(n0 + (ca >> 2), N - 1);   // clamp W rows (N tail)
    const int wr1 = min(n0 + (cb >> 2), N - 1);

    unsigned short* ldsA0 = As + (wave * 64) * 8;          // wave-uniform bases
    unsigned short* ldsA1 = As + (256 + wave * 64) * 8;
    unsigned short* ldsB0 = Bs + (wave * 64) * 8;
    unsigned short* ldsB1 = Bs + (256 + wave * 64) * 8;

    for (int k0 = 0; k0 < K; k0 += 32) {
        GLDS(A + (size_t)ar0 * K + k0 + k8a, ldsA0);
        GLDS(A + (size_t)ar1 * K + k0 + k8b, ldsA1);
        GLDS(W + (size_t)wr0 * K + k0 + k8a, ldsB0);
        GLDS(W + (size_t)wr1 * K + k0 + k8b, ldsB1);
        __syncthreads();
        bfrag af[4], bw[4];
#pragma unroll
        for (int i = 0; i < 4; i++)
            af[i] = *(const bfrag*)(As + (wm + i * 16 + lrow) * 32 + kq * 8);
#pragma unroll
        for (int j = 0; j < 4; j++)
            bw[j] = *(const bfrag*)(Bs + (wn + j * 16 + lrow) * 32 + kq * 8);
#pragma unroll
        for (int i = 0; i < 4; i++)
#pragma unroll
            for (int j = 0; j < 4; j++)
                acc[i][j] = __builtin_amdgcn_mfma_f32_16x16x32_bf16(af[i], bw[j], acc[i][j], 0, 0, 0);
        __syncthreads();
    }

    // epilogue: C/D layout col=lane&15, row=(lane>>4)*4+reg  [m89-verified]
#pragma unroll
    for (int j = 0; j < 4; j++) {
        int col  = n0 + wn + j * 16 + lrow;
        int colc = min(col, N - 1);
        float bs = 0.f;
        if (bias1) bs += bias1[colc];
        if (bias2) bs += bias2[colc];
        bool ok = (col < N);
#pragma unroll
        for (int i = 0; i < 4; i++) {
            int rbase = m0 + wm + i * 16 + kq * 4;
#pragma unroll
            for (int r = 0; r < 4; r++) {
                float v = acc[i][j][r] + bs;
                if (ok) outp[(size_t)(rbase + r) * N + col] = v;
            }
        }
    }
}

// ---------------------------------------------------------------------------
// Skewed fused step, launch k:
//   blocks   0..127 : layer1 @ t1 = k        (if 0 <= t1 < T)
//   blocks 128..255 : layer2 @ t2 = k-1      (if 0 <= t2 < T)
//   blocks 256..319 : attention @ ta = k-2   (if 0 <= ta < T), one block per b
// All deps are >= 1 launch apart: attn@ta reads Htop[ta+1] (written k-1);
// layer2@t2 reads H0[t2+1] (written k-1... same launch? no: H0[t2+1]=H0[k]
// written by layer1 at launch k-1). Launch ordering carries visibility.
// ---------------------------------------------------------------------------
__global__ __launch_bounds__(256)
void lstm_step(const unsigned short* __restrict__ Wbih,   // [L,2048,512] bf16
               const unsigned short* __restrict__ Wbhh,   // [L,2048,512] bf16
               const float* __restrict__ X0,              // [T*B,2048] fp32
               const float* __restrict__ b_ih,            // [L,4E] fp32
               const float* __restrict__ b_hh,            // [L,4E] fp32
               unsigned short* __restrict__ H0,           // [(T+1),B,E] bf16
               unsigned short* __restrict__ Htop,         // [(T+1),B,E] bf16
               float* __restrict__ c0, float* __restrict__ c1,
               const float* __restrict__ features,        // [B,R,E] fp32
               unsigned short* __restrict__ Z,            // [B*T,2E] bf16
               int t1, int t2, int ta)
{
    const int tid  = threadIdx.x;

    if (blockIdx.x >= 256) {
        // ---------------- attention for (b, ta) ----------------
        if (ta < 0) return;
        const int b = blockIdx.x - 256;
        const unsigned short* h = Htop + ((size_t)(ta + 1) * B_ + b) * E_;
        const float* f = features + (size_t)b * R_ * E_;
        const int wave = tid >> 6, lane = tid & 63;

        __shared__ float hf[E_];
        __shared__ float sc[64];
        hf[tid]       = bf2f((short)h[tid]);
        hf[256 + tid] = bf2f((short)h[256 + tid]);
        __syncthreads();

        for (int r = wave; r < R_; r += 4) {
            const float4* fr = (const float4*)(f + r * E_ + lane * 8);
            float4 v0 = fr[0], v1 = fr[1];
            const float* hp = hf + lane * 8;
            float s = v0.x * hp[0] + v0.y * hp[1] + v0.z * hp[2] + v0.w * hp[3]
                    + v1.x * hp[4] + v1.y * hp[5] + v1.z * hp[6] + v1.w * hp[7];
            for (int off = 32; off; off >>= 1) s += __shfl_down(s, off);
            if (lane == 0) sc[r] = s;
        }
        __syncthreads();
        if (tid < 64) {
            float v = (tid < R_) ? sc[tid] : -3.4e38f;
            float mx = v;
            for (int off = 32; off; off >>= 1) mx = fmaxf(mx, __shfl_xor(mx, off));
            float ex = (tid < R_) ? __expf(v - mx) : 0.f;
            float sum = ex;
            for (int off = 32; off; off >>= 1) sum += __shfl_xor(sum, off);
            if (tid < R_) sc[tid] = ex / sum;
        }
        __syncthreads();

        const int e0 = tid * 2;
        float cc0 = 0.f, cc1 = 0.f;
        for (int r = 0; r < R_; r++) {
            float a = sc[r];
            cc0 += a * f[r * E_ + e0];
            cc1 += a * f[r * E_ + e0 + 1];
        }
        unsigned short* zr = Z + (size_t)(b * T_ + ta) * (2 * E_);
        zr[e0] = h[e0]; zr[e0 + 1] = h[e0 + 1];          // bf16 copy of h_top
        zr[E_ + e0]     = f2bf(cc0);
        zr[E_ + e0 + 1] = f2bf(cc1);
        return;
    }

    // ---------------- LSTM cell ----------------
    const int layer = blockIdx.x >> 7;
    const int blk   = blockIdx.x & 127;
    const int wave = tid >> 6, lane = tid & 63;
    const int lrow = lane & 15, kq = lane >> 4;
    const int b0 = (blk & 3) * 16;
    const int e0 = (blk >> 2) * 16;
    const int wr = wave * 512 + e0 + lrow;   // W row (gate = wave)
    const size_t BE = (size_t)B_ * E_;

    const unsigned short *xin, *hprev, *Wih, *Whh;
    const float *pre, *bih, *bhh;
    unsigned short* hout; float* cst;

    if (layer == 0) {
        if (t1 < 0) return;
        xin = nullptr; Wih = nullptr;
        Whh = Wbhh;                                    // layer-0 W_hh
        pre = X0 + (size_t)t1 * B_ * 2048;             // x@Wih + biases (precomputed)
        bih = nullptr; bhh = nullptr;
        hprev = H0 + (size_t)t1 * BE;
        hout  = H0 + (size_t)(t1 + 1) * BE;
        cst = c0;
    } else {
        if (t2 < 0 || t2 >= T_) return;
        xin = H0 + (size_t)(t2 + 1) * BE;              // layer1 output @ t2
        Wih = Wbih + 2048 * 512;                       // layer-1 weights
        Whh = Wbhh + 2048 * 512;
        pre = nullptr;
        bih = b_ih + 2048; bhh = b_hh + 2048;
        hprev = Htop + (size_t)t2 * BE;
        hout  = Htop + (size_t)(t2 + 1) * BE;
        cst = c1;
    }

    ffrag acc = {0.f, 0.f, 0.f, 0.f};
    if (xin) {
#pragma unroll
        for (int k0 = 0; k0 < 512; k0 += 32) {
            bfrag a = *(const bfrag*)(xin + (b0 + lrow) * 512 + k0 + kq * 8);
            bfrag w = *(const bfrag*)(Wih + (size_t)wr * 512 + k0 + kq * 8);
            acc = __builtin_amdgcn_mfma_f32_16x16x32_bf16(a, w, acc, 0, 0, 0);
        }
    }
#pragma unroll
    for (int k0 = 0; k0 < 512; k0 += 32) {
        bfrag a = *(const bfrag*)(hprev + (b0 + lrow) * 512 + k0 + kq * 8);
        bfrag w = *(const bfrag*)(Whh + (size_t)wr * 512 + k0 + kq * 8);
        acc = __builtin_amdgcn_mfma_f32_16x16x32_bf16(a, w, acc, 0, 0, 0);
    }

    __shared__ float gb[4][16][17];   // [gate][b][e], +1 pad
#pragma unroll
    for (int r = 0; r < 4; r++) gb[wave][kq * 4 + r][lrow] = acc[r];
    __syncthreads();

    const int m = tid >> 4, el = tid & 15;
    const int b = b0 + m, e = e0 + el;
    float gi = gb[0][m][el], gf = gb[1][m][el], gg = gb[2][m][el], go = gb[3][m][el];
    if (pre) {
        const float* p = pre + (size_t)b * 2048;
        gi += p[e]; gf += p[512 + e]; gg += p[1024 + e]; go += p[1536 + e];
    }
    if (bih) {
        gi += bih[e]        + bhh[e];
        gf += bih[512 + e]  + bhh[512 + e];
        gg += bih[1024 + e] + bhh[1024 + e];
        go += bih[1536 + e] + bhh[1536 + e];
    }
    float cold = cst[(size_t)b * 512 + e];
    float cn = sigm(gf) * cold + sigm(gi) * tanhf(gg);
    float hn = sigm(go) * tanhf(cn);
    cst[(size_t)b * 512 + e]  = cn;
    hout[(size_t)b * 512 + e] = f2bf(hn);
}

// ---------------------------------------------------------------------------
// Init: mean_f -> c0/c1 (fp32) + h0 (bf16, both layers); gather+convert
// embeddings into Aemb [T*B, E] bf16.
// ---------------------------------------------------------------------------
__global__ __launch_bounds__(256)
void init_kernel(const float* __restrict__ features,
                 const int* __restrict__ captions,
                 const float* __restrict__ embed,
                 float* __restrict__ c0, float* __restrict__ c1,
                 unsigned short* __restrict__ H0, unsigned short* __restrict__ Htop,
                 unsigned short* __restrict__ Aemb)
{
    const int blk = blockIdx.x, tid = threadIdx.x;
    if (blk < 128) {
        int g = blk * 256 + tid;          // 0..B*E-1
        int b = g >> 9, e = g & 511;
        float s = 0.f;
        for (int r = 0; r < R_; r++) s += features[((size_t)b * R_ + r) * E_ + e];
        float mean = s * (1.f / 49.f);
        c0[g] = mean; c1[g] = mean;
        unsigned short mb = f2bf(mean);
        H0[g] = mb; Htop[g] = mb;
    } else {
        int idx = (blk - 128) * 256 + tid;        // chunk of 8 elems
        int row = idx >> 6, k8 = (idx & 63) * 8;  // row = t*B+b
        int bb = row & 63, tt = row >> 6;
        int tok = captions[bb * T_ + tt];
        const float4* s = (const float4*)(embed + (size_t)tok * E_ + k8);
        float4 a = s[0], bq = s[1];
        bfrag o;
        o[0] = (short)f2bf(a.x);  o[1] = (short)f2bf(a.y);
        o[2] = (short)f2bf(a.z);  o[3] = (short)f2bf(a.w);
        o[4] = (short)f2bf(bq.x); o[5] = (short)f2bf(bq.y);
        o[6] = (short)f2bf(bq.z); o[7] = (short)f2bf(bq.w);
        *(bfrag*)(Aemb + (size_t)row * E_ + k8) = o;
    }
}

// ---------------------------------------------------------------------------
extern "C" void kernel_launch(void* const* d_in, const int* in_sizes, int n_in,
                              void* d_out, int out_size, void* d_ws, size_t ws_size,
                              hipStream_t stream)
{
    const float* features = (const float*)d_in[0];
    const int*   captions = (const int*)d_in[1];
    const float* embed    = (const float*)d_in[2];
    const float* W_ih     = (const float*)d_in[3];
    const float* W_hh     = (const float*)d_in[4];
    const float* b_ih     = (const float*)d_in[5];
    const float* b_hh     = (const float*)d_in[6];
    const float* W_lin    = (const float*)d_in[7];
    const float* b_lin    = (const float*)d_in[8];
    float* out = (float*)d_out;

    char* ws = (char*)d_ws;
    float*          X0     = (float*)(ws);                       // [T*B,4E] fp32  16 MB
    unsigned short* H0     = (unsigned short*)(ws + 16777216);   // [(T+1),B,E] bf16
    unsigned short* Htop   = (unsigned short*)(ws + 18939904);   // [(T+1),B,E] bf16
    float*          c0     = (float*)(ws + 21102592);            // [B,E] fp32
    float*          c1     = (float*)(ws + 21233664);            // [B,E] fp32
    unsigned short* Z      = (unsigned short*)(ws + 21364736);   // [B*T,2E] bf16
    unsigned short* Aemb   = (unsigned short*)(ws + 25559040);   // [T*B,E] bf16
    unsigned short* Wb_ih  = (unsigned short*)(ws + 27656192);   // [L,4E,E] bf16
    unsigned short* Wb_hh  = (unsigned short*)(ws + 31850496);   // [L,4E,E] bf16
    unsigned short* Wb_lin = (unsigned short*)(ws + 36044800);   // [V,2E] bf16 61.4 MB

    // fp32 -> bf16 weight conversions
    cvt_kernel<<<1024, 256, 0, stream>>>(W_ih, Wb_ih, 2 * 2048 * 512 / 8);
    cvt_kernel<<<1024, 256, 0, stream>>>(W_hh, Wb_hh, 2 * 2048 * 512 / 8);
    cvt_kernel<<<15000, 256, 0, stream>>>(W_lin, Wb_lin, V_ * 1024 / 8);

    init_kernel<<<640, 256, 0, stream>>>(features, captions, embed, c0, c1, H0, Htop, Aemb);

    // X0 = Aemb @ W_ih[0]^T + b_ih[0] + b_hh[0]   (fp32, [T*B,4E])
    gemm_bt<<<dim3(16, 16), 256, 0, stream>>>(Aemb, Wb_ih, b_ih, b_hh, X0, 2048, 2048, 512);

    // Skewed recurrence + fused attention:
    // launch k = { layer1@k, layer2@(k-1), attn@(k-2) }, k = 0..T+1
    for (int k = 0; k <= T_ + 1; k++) {
        lstm_step<<<320, 256, 0, stream>>>(Wb_ih, Wb_hh, X0, b_ih, b_hh,
                                           H0, Htop, c0, c1,
                                           features, Z,
                                           (k < T_) ? k : -1, k - 1, k - 2);
    }

    // logits = Z @ W_lin^T + b_lin  -> fp32 out [B*T, V]
    gemm_bt<<<dim3(16, 235), 256, 0, stream>>>(Z, Wb_lin, b_lin, nullptr, out, 2048, V_, 1024);

    (void)in_sizes; (void)n_in; (void)out_size; (void)ws_size;
}

// Round 4
// 930.914 us; speedup vs baseline: 1.7892x; 1.0572x over previous
//
#include <hip/hip_runtime.h>

// Decoder: B=64, T=32, R=49, E=512, L=2, V=30000. fp32 in/out, bf16 MFMA inside.
#define B_ 64
#define T_ 32
#define R_ 49
#define E_ 512
#define V_ 30000

using bfrag = __attribute__((ext_vector_type(8))) short;   // 8 bf16 (4 VGPRs)
using ffrag = __attribute__((ext_vector_type(4))) float;   // 4 fp32 acc

__device__ __forceinline__ float bf2f(short u) {
    union { unsigned u32; float f; } x;
    x.u32 = ((unsigned)(unsigned short)u) << 16;
    return x.f;
}
__device__ __forceinline__ unsigned short f2bf(float f) {
    union { float f; unsigned u; } x; x.f = f;
    unsigned r = x.u + 0x7fffu + ((x.u >> 16) & 1u);   // RNE
    return (unsigned short)(r >> 16);
}
__device__ __forceinline__ float sigm(float x) { return 1.f / (1.f + __expf(-x)); }

#define GLDS(g, l) __builtin_amdgcn_global_load_lds( \
    (const __attribute__((address_space(1))) void*)(g), \
    (__attribute__((address_space(3))) void*)(l), 16, 0, 0)

// --- device-coherent (cross-XCD) helpers -----------------------------------
// Stores: atomicExch (RMW) — performed at the device coherence point.
// Loads:  agent-scope relaxed atomic loads — sc-bits bypass the per-XCD L2.
__device__ __forceinline__ bfrag ld_frag_coh(const unsigned short* p) {
    const unsigned long long* q = (const unsigned long long*)p;
    unsigned long long d0 = __hip_atomic_load(q,     __ATOMIC_RELAXED, __HIP_MEMORY_SCOPE_AGENT);
    unsigned long long d1 = __hip_atomic_load(q + 1, __ATOMIC_RELAXED, __HIP_MEMORY_SCOPE_AGENT);
    union { unsigned long long u[2]; bfrag f; } x;
    x.u[0] = d0; x.u[1] = d1;
    return x.f;
}

// Thread-0 spins; every 16th poll is an RMW read (guaranteed fresh) so a
// stale-sc-load pathology can slow us down but can never hang the kernel.
__device__ __forceinline__ void wait_flag(unsigned* f, unsigned target) {
    if (threadIdx.x == 0) {
        unsigned it = 0;
        for (;;) {
            unsigned v = ((++it) & 15u)
                ? __hip_atomic_load(f, __ATOMIC_RELAXED, __HIP_MEMORY_SCOPE_AGENT)
                : atomicAdd(f, 0u);
            if (v >= target) break;
            __builtin_amdgcn_s_sleep(16);
        }
    }
    __syncthreads();
}

// ---------------------------------------------------------------------------
// fp32 -> bf16 bulk convert. n8 = elem_count/8.
// ---------------------------------------------------------------------------
__global__ __launch_bounds__(256)
void cvt_kernel(const float* __restrict__ src, unsigned short* __restrict__ dst, int n8)
{
    int i = blockIdx.x * 256 + threadIdx.x;
    if (i >= n8) return;
    const float4* s = (const float4*)src + (size_t)i * 2;
    float4 a = s[0], b = s[1];
    bfrag o;
    o[0] = (short)f2bf(a.x); o[1] = (short)f2bf(a.y);
    o[2] = (short)f2bf(a.z); o[3] = (short)f2bf(a.w);
    o[4] = (short)f2bf(b.x); o[5] = (short)f2bf(b.y);
    o[6] = (short)f2bf(b.z); o[7] = (short)f2bf(b.w);
    *(bfrag*)(dst + (size_t)i * 8) = o;
}

// ---------------------------------------------------------------------------
// C = A @ W^T (+bias1+bias2), fp32 out. A:[M,K] bf16, W:[N,K] bf16, bias fp32.
// m97 structure: 128x128 tile, BK=32, global_load_lds w=16, mfma 16x16x32 bf16.
// No XCD swizzle: R1 A/B showed FETCH 252->149 MB but dur +5% (not fetch-bound).
// ---------------------------------------------------------------------------
__global__ __launch_bounds__(256)
void gemm_bt(const unsigned short* __restrict__ A,
             const unsigned short* __restrict__ W,
             const float* __restrict__ bias1,
             const float* __restrict__ bias2,
             float* __restrict__ outp,
             int M, int N, int K)
{
    __shared__ __align__(16) unsigned short As[128 * 32];
    __shared__ __align__(16) unsigned short Bs[128 * 32];
    const int tid  = threadIdx.x;
    const int wave = tid >> 6, lane = tid & 63;
    const int lrow = lane & 15, kq = lane >> 4;
    const int m0 = blockIdx.x * 128, n0 = blockIdx.y * 128;
    const int wm = (wave >> 1) * 64, wn = (wave & 1) * 64;

    ffrag acc[4][4];
#pragma unroll
    for (int i = 0; i < 4; i++)
#pragma unroll
        for (int j = 0; j < 4; j++) acc[i][j] = ffrag{0.f, 0.f, 0.f, 0.f};

    const int ca = tid, cb = 256 + tid;
    const int ar0 = m0 + (ca >> 2), ar1 = m0 + (cb >> 2);
    const int k8a = (ca & 3) * 8, k8b = (cb & 3) * 8;
    const int wr0 = min(n0 + (ca >> 2), N - 1);   // clamp W rows (N tail)
    const int wr1 = min(n0 + (cb >> 2), N - 1);

    unsigned short* ldsA0 = As + (wave * 64) * 8;          // wave-uniform bases
    unsigned short* ldsA1 = As + (256 + wave * 64) * 8;
    unsigned short* ldsB0 = Bs + (wave * 64) * 8;
    unsigned short* ldsB1 = Bs + (256 + wave * 64) * 8;

    for (int k0 = 0; k0 < K; k0 += 32) {
        GLDS(A + (size_t)ar0 * K + k0 + k8a, ldsA0);
        GLDS(A + (size_t)ar1 * K + k0 + k8b, ldsA1);
        GLDS(W + (size_t)wr0 * K + k0 + k8a, ldsB0);
        GLDS(W + (size_t)wr1 * K + k0 + k8b, ldsB1);
        __syncthreads();
        bfrag af[4], bw[4];
#pragma unroll
        for (int i = 0; i < 4; i++)
            af[i] = *(const bfrag*)(As + (wm + i * 16 + lrow) * 32 + kq * 8);
#pragma unroll
        for (int j = 0; j < 4; j++)
            bw[j] = *(const bfrag*)(Bs + (wn + j * 16 + lrow) * 32 + kq * 8);
#pragma unroll
        for (int i = 0; i < 4; i++)
#pragma unroll
            for (int j = 0; j < 4; j++)
                acc[i][j] = __builtin_amdgcn_mfma_f32_16x16x32_bf16(af[i], bw[j], acc[i][j], 0, 0, 0);
        __syncthreads();
    }

    // epilogue: C/D layout col=lane&15, row=(lane>>4)*4+reg  [m89-verified]
#pragma unroll
    for (int j = 0; j < 4; j++) {
        int col  = n0 + wn + j * 16 + lrow;
        int colc = min(col, N - 1);
        float bs = 0.f;
        if (bias1) bs += bias1[colc];
        if (bias2) bs += bias2[colc];
        bool ok = (col < N);
#pragma unroll
        for (int i = 0; i < 4; i++) {
            int rbase = m0 + wm + i * 16 + kq * 4;
#pragma unroll
            for (int r = 0; r < 4; r++) {
                float v = acc[i][j][r] + bs;
                if (ok) outp[(size_t)(rbase + r) * N + col] = v;
            }
        }
    }
}

// ---------------------------------------------------------------------------
// Persistent skewed 2-layer LSTM, flag-pipelined (NO grid.sync).
// 256 blocks (1/CU, cooperative for co-residency). Blocks 0..127 = layer0,
// 128..255 = layer1. Block (layer, btile=blk&3, e0=(blk>>2)*16) owns its
// output slice for ALL t. Weights staged ONCE into LDS (128 KB, frag order).
// Cross-block h exchange: atomicExch stores (LLC-coherent) + agent atomic
// loads. flagX[t*4+btile]==32  <=>  HX[t] rows [btile*16,+16) complete.
// ---------------------------------------------------------------------------
__global__ __launch_bounds__(256, 1)
void lstm_persist(const unsigned short* __restrict__ Wbih,   // [L,2048,512] bf16
                  const unsigned short* __restrict__ Wbhh,   // [L,2048,512] bf16
                  const unsigned short* __restrict__ Aemb,   // [T*B,E] bf16
                  const float* __restrict__ b_ih,            // [L,4E] fp32
                  const float* __restrict__ b_hh,            // [L,4E] fp32
                  unsigned short* __restrict__ H0,           // [(T+1),B,E] bf16
                  unsigned short* __restrict__ Htop,         // [(T+1),B,E] bf16
                  const float* __restrict__ c0,
                  const float* __restrict__ c1,
                  unsigned* __restrict__ flag0,              // [(T+1)*4]
                  unsigned* __restrict__ flag1)              // [(T+1)*4]
{
    // sW: [mat(2)][gate(4)][kiter(16)][lane(64)][8 bf16] = 128 KB
    __shared__ __align__(16) unsigned short sW[2 * 4 * 16 * 512];
    __shared__ float gb[4][16][17];            // [gate][b][e], +1 pad
    __shared__ unsigned short hb[16][16];      // h-out staging for packed stores

    const int layer = blockIdx.x >> 7;
    const int blk   = blockIdx.x & 127;
    const int tid  = threadIdx.x;
    const int wave = tid >> 6, lane = tid & 63;
    const int lrow = lane & 15, kq = lane >> 4;
    const int bt = blk & 3;
    const int b0 = bt * 16;
    const int e0 = (blk >> 2) * 16;
    const int wr = wave * 512 + e0 + lrow;   // W row (gate = wave)
    const size_t BE = (size_t)B_ * E_;

    const unsigned short* Wih = Wbih + (size_t)layer * 2048 * 512;
    const unsigned short* Whh = Wbhh + (size_t)layer * 2048 * 512;

    // stage weights into LDS once (per-lane global src, wave-uniform dst+lane*16B)
#pragma unroll
    for (int it = 0; it < 16; ++it)
        GLDS(Wih + (size_t)wr * 512 + it * 32 + kq * 8, sW + (size_t)(wave * 16 + it) * 512);
#pragma unroll
    for (int it = 0; it < 16; ++it)
        GLDS(Whh + (size_t)wr * 512 + it * 32 + kq * 8, sW + (size_t)((4 + wave) * 16 + it) * 512);

    // per-thread elementwise coords + bias preload + register cell state
    const int m = tid >> 4, el = tid & 15;
    const int b = b0 + m, e = e0 + el;
    const float* bih = b_ih + layer * 2048;
    const float* bhh = b_hh + layer * 2048;
    const float bi = bih[e]        + bhh[e];
    const float bf = bih[512 + e]  + bhh[512 + e];
    const float bg = bih[1024 + e] + bhh[1024 + e];
    const float bo = bih[1536 + e] + bhh[1536 + e];
    float creg = (layer ? c1 : c0)[(size_t)b * 512 + e];

    const unsigned short* sWi = sW + (size_t)wave * 16 * 512;        // this gate, Wih
    const unsigned short* sWh = sW + (size_t)(4 + wave) * 16 * 512;  // this gate, Whh

    __syncthreads();   // drains GLDS (vmcnt) + block barrier

    for (int t = 0; t < T_; ++t) {
        // ---- wait for inputs (self-pipelining; no global barrier) ----
        if (layer == 0) {
            if (t >= 1) wait_flag(flag0 + (t * 4 + bt), 32);          // H0[t]
        } else {
            wait_flag(flag0 + ((t + 1) * 4 + bt), 32);                // H0[t+1]
            if (t >= 1) wait_flag(flag1 + (t * 4 + bt), 32);          // Htop[t]
        }

        const unsigned short* hprev = (layer ? Htop : H0) + (size_t)t * BE;
        unsigned short* hout        = (layer ? Htop : H0) + (size_t)(t + 1) * BE;

        ffrag acc = {0.f, 0.f, 0.f, 0.f};
        if (layer == 0) {
            const unsigned short* xin = Aemb + (size_t)t * BE;   // pre-kernel data: plain loads
#pragma unroll
            for (int i = 0; i < 16; ++i) {
                bfrag a = *(const bfrag*)(xin + (b0 + lrow) * 512 + i * 32 + kq * 8);
                bfrag w = *(const bfrag*)(sWi + (i * 64 + lane) * 8);
                acc = __builtin_amdgcn_mfma_f32_16x16x32_bf16(a, w, acc, 0, 0, 0);
            }
        } else {
            const unsigned short* xin = H0 + (size_t)(t + 1) * BE; // intra-kernel: coherent
#pragma unroll
            for (int i = 0; i < 16; ++i) {
                bfrag a = ld_frag_coh(xin + (b0 + lrow) * 512 + i * 32 + kq * 8);
                bfrag w = *(const bfrag*)(sWi + (i * 64 + lane) * 8);
                acc = __builtin_amdgcn_mfma_f32_16x16x32_bf16(a, w, acc, 0, 0, 0);
            }
        }
#pragma unroll
        for (int i = 0; i < 16; ++i) {
            bfrag a = ld_frag_coh(hprev + (b0 + lrow) * 512 + i * 32 + kq * 8);
            bfrag w = *(const bfrag*)(sWh + (i * 64 + lane) * 8);
            acc = __builtin_amdgcn_mfma_f32_16x16x32_bf16(a, w, acc, 0, 0, 0);
        }

#pragma unroll
        for (int r = 0; r < 4; r++) gb[wave][kq * 4 + r][lrow] = acc[r];
        __syncthreads();

        float gi = gb[0][m][el] + bi;
        float gf = gb[1][m][el] + bf;
        float gg = gb[2][m][el] + bg;
        float go = gb[3][m][el] + bo;
        float cn = sigm(gf) * creg + sigm(gi) * tanhf(gg);
        float hn = sigm(go) * tanhf(cn);
        creg = cn;
        hb[m][el] = f2bf(hn);
        __syncthreads();

        // packed 8B coherent stores of the 16x16 h slice (64 threads x 4 bf16)
        if (tid < 64) {
            const int mm = tid >> 2, qp = tid & 3;
            const unsigned short* hp = &hb[mm][qp * 4];
            unsigned long long v = (unsigned long long)hp[0]
                                 | ((unsigned long long)hp[1] << 16)
                                 | ((unsigned long long)hp[2] << 32)
                                 | ((unsigned long long)hp[3] << 48);
            atomicExch((unsigned long long*)(hout + (size_t)(b0 + mm) * 512 + e0) + qp, v);
        }
        __syncthreads();   // drains vmcnt: h stores globally visible

        if (tid == 0)
            atomicAdd((layer ? flag1 : flag0) + ((t + 1) * 4 + bt), 1u);
    }
}

// ---------------------------------------------------------------------------
// Attention over all (b,t) at once. block = one (b,t).
// Z[b*T+t] = [h_top(bf16 copy) | context(bf16)]. features fp32.
// ---------------------------------------------------------------------------
__global__ __launch_bounds__(256)
void attn_kernel(const float* __restrict__ features,          // [B,R,E] fp32
                 const unsigned short* __restrict__ Htop,     // [(T+1),B,E] bf16
                 unsigned short* __restrict__ Z)               // [B*T, 2E] bf16
{
    const int bt = blockIdx.x;            // = b*T + t
    const int b = bt >> 5, t = bt & 31;
    const unsigned short* h = Htop + ((size_t)(t + 1) * B_ + b) * E_;
    const float* f = features + (size_t)b * R_ * E_;
    const int tid = threadIdx.x, wave = tid >> 6, lane = tid & 63;

    __shared__ float hf[E_];
    __shared__ float sc[64];
    hf[tid]       = bf2f((short)h[tid]);
    hf[256 + tid] = bf2f((short)h[256 + tid]);
    __syncthreads();

    for (int r = wave; r < R_; r += 4) {
        const float4* fr = (const float4*)(f + r * E_ + lane * 8);
        float4 v0 = fr[0], v1 = fr[1];
        const float* hp = hf + lane * 8;
        float s = v0.x * hp[0] + v0.y * hp[1] + v0.z * hp[2] + v0.w * hp[3]
                + v1.x * hp[4] + v1.y * hp[5] + v1.z * hp[6] + v1.w * hp[7];
        for (int off = 32; off; off >>= 1) s += __shfl_down(s, off);
        if (lane == 0) sc[r] = s;
    }
    __syncthreads();
    if (tid < 64) {
        float v = (tid < R_) ? sc[tid] : -3.4e38f;
        float mx = v;
        for (int off = 32; off; off >>= 1) mx = fmaxf(mx, __shfl_xor(mx, off));
        float ex = (tid < R_) ? __expf(v - mx) : 0.f;
        float sum = ex;
        for (int off = 32; off; off >>= 1) sum += __shfl_xor(sum, off);
        if (tid < R_) sc[tid] = ex / sum;
    }
    __syncthreads();

    const int e0 = tid * 2;
    float c0 = 0.f, c1 = 0.f;
    for (int r = 0; r < R_; r++) {
        float a = sc[r];
        c0 += a * f[r * E_ + e0];
        c1 += a * f[r * E_ + e0 + 1];
    }
    unsigned short* zr = Z + (size_t)bt * (2 * E_);
    zr[e0] = h[e0]; zr[e0 + 1] = h[e0 + 1];          // bf16 copy of h_top
    zr[E_ + e0]     = f2bf(c0);
    zr[E_ + e0 + 1] = f2bf(c1);
}

// ---------------------------------------------------------------------------
// Init: mean_f -> c0/c1 (fp32) + h0 (bf16, both layers); gather+convert
// embeddings into Aemb [T*B, E] bf16; zero the pipeline flags.
// ---------------------------------------------------------------------------
__global__ __launch_bounds__(256)
void init_kernel(const float* __restrict__ features,
                 const int* __restrict__ captions,
                 const float* __restrict__ embed,
                 float* __restrict__ c0, float* __restrict__ c1,
                 unsigned short* __restrict__ H0, unsigned short* __restrict__ Htop,
                 unsigned short* __restrict__ Aemb,
                 unsigned* __restrict__ flags)     // [2*(T+1)*4]
{
    const int blk = blockIdx.x, tid = threadIdx.x;
    if (blk < 128) {
        if (blk == 0) {
            for (int i = tid; i < 2 * (T_ + 1) * 4; i += 256) flags[i] = 0;
        }
        int g = blk * 256 + tid;          // 0..B*E-1
        int b = g >> 9, e = g & 511;
        float s = 0.f;
        for (int r = 0; r < R_; r++) s += features[((size_t)b * R_ + r) * E_ + e];
        float mean = s * (1.f / 49.f);
        c0[g] = mean; c1[g] = mean;
        unsigned short mb = f2bf(mean);
        H0[g] = mb; Htop[g] = mb;
    } else {
        int idx = (blk - 128) * 256 + tid;        // chunk of 8 elems
        int row = idx >> 6, k8 = (idx & 63) * 8;  // row = t*B+b
        int bb = row & 63, tt = row >> 6;
        int tok = captions[bb * T_ + tt];
        const float4* s = (const float4*)(embed + (size_t)tok * E_ + k8);
        float4 a = s[0], bq = s[1];
        bfrag o;
        o[0] = (short)f2bf(a.x);  o[1] = (short)f2bf(a.y);
        o[2] = (short)f2bf(a.z);  o[3] = (short)f2bf(a.w);
        o[4] = (short)f2bf(bq.x); o[5] = (short)f2bf(bq.y);
        o[6] = (short)f2bf(bq.z); o[7] = (short)f2bf(bq.w);
        *(bfrag*)(Aemb + (size_t)row * E_ + k8) = o;
    }
}

// ---------------------------------------------------------------------------
extern "C" void kernel_launch(void* const* d_in, const int* in_sizes, int n_in,
                              void* d_out, int out_size, void* d_ws, size_t ws_size,
                              hipStream_t stream)
{
    const float* features = (const float*)d_in[0];
    const int*   captions = (const int*)d_in[1];
    const float* embed    = (const float*)d_in[2];
    const float* W_ih     = (const float*)d_in[3];
    const float* W_hh     = (const float*)d_in[4];
    const float* b_ih     = (const float*)d_in[5];
    const float* b_hh     = (const float*)d_in[6];
    const float* W_lin    = (const float*)d_in[7];
    const float* b_lin    = (const float*)d_in[8];
    float* out = (float*)d_out;

    char* ws = (char*)d_ws;
    unsigned*       flags  = (unsigned*)(ws);                    // [264] (old X0 area)
    unsigned short* H0     = (unsigned short*)(ws + 16777216);   // [(T+1),B,E] bf16
    unsigned short* Htop   = (unsigned short*)(ws + 18939904);   // [(T+1),B,E] bf16
    float*          c0     = (float*)(ws + 21102592);            // [B,E] fp32
    float*          c1     = (float*)(ws + 21233664);            // [B,E] fp32
    unsigned short* Z      = (unsigned short*)(ws + 21364736);   // [B*T,2E] bf16
    unsigned short* Aemb   = (unsigned short*)(ws + 25559040);   // [T*B,E] bf16
    unsigned short* Wb_ih  = (unsigned short*)(ws + 27656192);   // [L,4E,E] bf16
    unsigned short* Wb_hh  = (unsigned short*)(ws + 31850496);   // [L,4E,E] bf16
    unsigned short* Wb_lin = (unsigned short*)(ws + 36044800);   // [V,2E] bf16 61.4 MB

    // fp32 -> bf16 weight conversions
    cvt_kernel<<<1024, 256, 0, stream>>>(W_ih, Wb_ih, 2 * 2048 * 512 / 8);
    cvt_kernel<<<1024, 256, 0, stream>>>(W_hh, Wb_hh, 2 * 2048 * 512 / 8);
    cvt_kernel<<<15000, 256, 0, stream>>>(W_lin, Wb_lin, V_ * 1024 / 8);

    init_kernel<<<640, 256, 0, stream>>>(features, captions, embed, c0, c1, H0, Htop,
                                         Aemb, flags);

    // Whole recurrence in ONE cooperative launch, flag-pipelined (no grid.sync).
    {
        const unsigned short* a0 = Wb_ih; const unsigned short* a1 = Wb_hh;
        const unsigned short* a2 = Aemb;
        const float* a3 = b_ih; const float* a4 = b_hh;
        unsigned short* a5 = H0; unsigned short* a6 = Htop;
        const float* a7 = c0; const float* a8 = c1;
        unsigned* a9 = flags; unsigned* a10 = flags + (T_ + 1) * 4;
        void* args[] = { &a0, &a1, &a2, &a3, &a4, &a5, &a6, &a7, &a8, &a9, &a10 };
        hipLaunchCooperativeKernel((void*)lstm_persist, dim3(256), dim3(256),
                                   args, 0, stream);
    }

    attn_kernel<<<B_ * T_, 256, 0, stream>>>(features, Htop, Z);

    // logits = Z @ W_lin^T + b_lin  -> fp32 out [B*T, V]
    gemm_bt<<<dim3(16, 235), 256, 0, stream>>>(Z, Wb_lin, b_lin, nullptr, out, 2048, V_, 1024);

    (void)in_sizes; (void)n_in; (void)out_size; (void)ws_size;
}